// Round 19
// baseline (177.434 us; speedup 1.0000x reference)
//
#include <hip/hip_runtime.h>
#include <hip/hip_bf16.h>
#include <cstdint>
#include <cstddef>

typedef unsigned short u16;
typedef __bf16 bf16x8 __attribute__((ext_vector_type(8)));
typedef float  f32x4  __attribute__((ext_vector_type(4)));
typedef u16    u16x8  __attribute__((ext_vector_type(8)));
typedef u16    u16x4  __attribute__((ext_vector_type(4)));
typedef short  s16x4  __attribute__((ext_vector_type(4)));

#define MFMA16(A_, B_, C_) __builtin_amdgcn_mfma_f32_16x16x32_bf16((A_), (B_), (C_), 0, 0, 0)
#define MFMA16K16(A_, B_, C_) __builtin_amdgcn_mfma_f32_16x16x16bf16_1k((A_), (B_), (C_), 0, 0, 0)

#define LOG2E 1.4426950408889634f

#if __has_builtin(__builtin_amdgcn_exp2f)
#define EXP2(x) __builtin_amdgcn_exp2f(x)
#else
#define EXP2(x) exp2f(x)
#endif

__device__ __forceinline__ u16 f2bf(float f) {
  return __builtin_bit_cast(u16, (__bf16)f);
}
__device__ __forceinline__ float bf2f(u16 v) {
  return (float)__builtin_bit_cast(__bf16, v);
}

// async global->LDS, 16B per lane. lds must be wave-uniform base; HW adds lane*16.
__device__ __forceinline__ void async16(u16* lds, const u16* g) {
  __builtin_amdgcn_global_load_lds(
      (const __attribute__((address_space(1))) unsigned int*)g,
      (__attribute__((address_space(3))) unsigned int*)lds, 16, 0, 0);
}

// ---------------- prep: x cvt + weight cvts + bn folds (pre-GEMM deps only) ----------------

__device__ __forceinline__ void cvt4(const float* src, u16* dst, int i) {
  const float4 v = ((const float4*)src)[i];
  u16x4 o;
  o[0] = f2bf(v.x); o[1] = f2bf(v.y); o[2] = f2bf(v.z); o[3] = f2bf(v.w);
  ((u16x4*)dst)[i] = o;
}

__device__ __forceinline__ void bn1(const float* g, const float* b, const float* rm,
                                    const float* rv, float* alpha, float* beta,
                                    int i, float scale) {
  float a0 = g[i] * rsqrtf(rv[i] + 1e-5f);
  alpha[i] = a0 * scale;
  beta[i]  = (b[i] - rm[i] * a0) * scale;
}

__global__ void prep_all(
    const float* __restrict__ x, u16* __restrict__ x_bf,
    const float* __restrict__ Wkv, const float* __restrict__ Wq, const float* __restrict__ Wp,
    u16* __restrict__ wkv_bf, u16* __restrict__ wq_bf, u16* __restrict__ wp_bf,
    const float* __restrict__ g_kv, const float* __restrict__ b_kv,
    const float* __restrict__ rm_kv, const float* __restrict__ rv_kv,
    float* __restrict__ al_kv, float* __restrict__ be_kv,
    const float* __restrict__ g_q, const float* __restrict__ b_q,
    const float* __restrict__ rm_q, const float* __restrict__ rv_q,
    float* __restrict__ al_q, float* __restrict__ be_q,
    const float* __restrict__ g_p, const float* __restrict__ b_p,
    const float* __restrict__ rm_p, const float* __restrict__ rv_p,
    float* __restrict__ al_p, float* __restrict__ be_p) {
  const int bid = blockIdx.x, t = threadIdx.x;
  if (bid < 10240) {                       // x: 2621440 float4
    cvt4(x, x_bf, bid * 256 + t);
  } else if (bid < 10624) {
    cvt4(Wkv, wkv_bf, (bid - 10240) * 256 + t);
  } else if (bid < 10752) {
    cvt4(Wq, wq_bf, (bid - 10624) * 256 + t);
  } else if (bid < 11136) {
    cvt4(Wp, wp_bf, (bid - 10752) * 256 + t);
  } else if (bid < 11142) {
    bn1(g_kv, b_kv, rm_kv, rv_kv, al_kv, be_kv, (bid - 11136) * 256 + t, 1.0f);
  } else if (bid < 11144) {
    bn1(g_q, b_q, rm_q, rv_q, al_q, be_q, (bid - 11142) * 256 + t, 0.125f * LOG2E);
  } else {
    const int i = (bid - 11144) * 256 + t;
    if (i < 384) bn1(g_p, b_p, rm_p, rv_p, al_p, be_p, i, 1.0f);
  }
}

// ---------------- fused GEMM: kv (LDS-repack epilogue) + q + bias-table expand ----------------
// bias expansion only feeds attn (no GEMM dependency) -> runs as tail blocks of
// this dispatch, overlapping the kv/q drain instead of serializing before it.
// K phys per (bh, kt32): 32 rows x 64ch, 16B chunk c at c^(r&7)     (b128 reads)
// V phys: 128 d x 32 keys, 8B chunk hc at (hc+(d>>1))&7             (b64 reads)

__device__ __forceinline__ void gemm_kv_part(
    u16* S, int bid,
    const u16* __restrict__ A, const u16* __restrict__ Wt,
    const float* __restrict__ alpha, const float* __restrict__ beta,
    u16* __restrict__ k_buf, u16* __restrict__ vt_buf) {
  u16* As = S;
  u16* Bs = S + 8192;
  const int tid  = threadIdx.x;
  const int lane = tid & 63;
  const int w    = tid >> 6;
  const int wr   = (w >> 1) * 64, wc = (w & 1) * 64;
  const int lr   = lane >> 4, lc = lane & 15;
  const int m0   = (bid % 320) * 128;
  const int n0   = (bid / 320) * 128;
  const int scol  = (lane & 7) * 8;
  f32x4 acc[4][4] = {};

  for (int kt = 0; kt < 256; kt += 64) {
    if (kt) __syncthreads();
#pragma unroll
    for (int i = 0; i < 4; ++i) {
      const int row = w * 32 + i * 8 + (lane >> 3);
      async16(&As[(w * 32 + i * 8) * 64], A  + (size_t)(m0 + row) * 256 + kt + scol);
      async16(&Bs[(w * 32 + i * 8) * 64], Wt + (size_t)(n0 + row) * 256 + kt + scol);
    }
    __syncthreads();
#pragma unroll
    for (int kk = 0; kk < 2; ++kk) {
      bf16x8 af[4], bff[4];
#pragma unroll
      for (int m = 0; m < 4; ++m)
        af[m] = *(const bf16x8*)(&As[(wr + m * 16 + lc) * 64 + kk * 32 + lr * 8]);
#pragma unroll
      for (int n = 0; n < 4; ++n)
        bff[n] = *(const bf16x8*)(&Bs[(wc + n * 16 + lc) * 64 + kk * 32 + lr * 8]);
#pragma unroll
      for (int m = 0; m < 4; ++m)
#pragma unroll
        for (int n = 0; n < 4; ++n)
          acc[m][n] = MFMA16(af[m], bff[n], acc[m][n]);
    }
  }

  __syncthreads();
  const int jr   = lr * 4;
  const int b    = m0 / 1280;
  const int np0  = m0 - b * 1280;
  const int kt0  = np0 >> 5;
  const int hh   = w & 1;
  const int c0   = n0 + hh * 64;
  const int head = c0 / 192;
  const int rem  = c0 - head * 192;
  u16* R = S + hh * 8192;
  (void)head;

#pragma unroll
  for (int m = 0; m < 4; ++m) {
    const int lrow = (w >> 1) * 64 + m * 16 + jr;
    const int ktl  = lrow >> 5;
    const int kl   = lrow & 31;
#pragma unroll
    for (int n = 0; n < 4; ++n) {
      const int ch = n * 16 + lc;
      const int c  = c0 + ch;
      const float al = alpha[c], be = beta[c];
      if (rem == 0) {
#pragma unroll
        for (int j = 0; j < 4; ++j) {
          const int r = kl + j;
          R[ktl * 2048 + (r << 6) + (((ch >> 3) ^ (r & 7)) << 3) + (ch & 7)] =
              f2bf(acc[m][n][j] * al + be);
        }
      } else {
        const int d = (rem - 64) + ch;
        u16x4 pk;
#pragma unroll
        for (int j = 0; j < 4; ++j) pk[j] = f2bf(acc[m][n][j] * al + be);
        *(u16x4*)(&R[ktl * 2048 + ch * 32 + ((((kl >> 2) + (d >> 1)) & 7) << 2)]) = pk;
      }
    }
  }
  __syncthreads();

#pragma unroll
  for (int g2 = 0; g2 < 2; ++g2) {
    const int c0g  = n0 + g2 * 64;
    const int hd   = c0g / 192;
    const int remg = c0g - hd * 192;
    const size_t bhg = (size_t)(b * 8 + hd);
    const u16* Rg = S + g2 * 8192;
    if (remg == 0) {
      u16* dst = k_buf + ((bhg * 40 + kt0) << 11);
#pragma unroll
      for (int i = 0; i < 4; ++i)
        *(u16x8*)(dst + i * 2048 + tid * 8) = *(const u16x8*)(Rg + i * 2048 + tid * 8);
    } else {
      const int dbase = remg - 64;
#pragma unroll
      for (int i = 0; i < 4; ++i)
        *(u16x8*)(vt_buf + ((bhg * 40 + kt0 + i) << 12) + dbase * 32 + tid * 8) =
            *(const u16x8*)(Rg + i * 2048 + tid * 8);
    }
  }
}

__device__ __forceinline__ int sub_src_row(int qr) {
  if (qr < 256) return ((qr >> 4) * 64) + ((qr & 15) * 2);
  int rr = qr - 256;
  return 1024 + ((rr >> 3) * 32) + ((rr & 7) * 2);
}

__device__ __forceinline__ void gemm_q_part(
    u16* S, int id2,
    const u16* __restrict__ X, const u16* __restrict__ Wt,
    const float* __restrict__ alpha, const float* __restrict__ beta,
    u16* __restrict__ q_buf) {
  u16* As = S;
  u16* Bs = S + 8192;
  const int tid  = threadIdx.x;
  const int lane = tid & 63;
  const int w    = tid >> 6;
  const int wr   = (w >> 1) * 64, wc = (w & 1) * 64;
  const int lr   = lane >> 4, lc = lane & 15;
  const int m0   = (id2 % 80) * 128;
  const int n0   = (id2 / 80) * 128;
  const int scol  = (lane & 7) * 8;
  f32x4 acc[4][4] = {};

  for (int kt = 0; kt < 256; kt += 64) {
    if (kt) __syncthreads();
#pragma unroll
    for (int i = 0; i < 4; ++i) {
      const int row = w * 32 + i * 8 + (lane >> 3);
      const int gr  = m0 + row;
      const int bb  = gr / 320;
      const int qr  = gr - bb * 320;
      async16(&As[(w * 32 + i * 8) * 64],
              X + (size_t)(bb * 1280 + sub_src_row(qr)) * 256 + kt + scol);
      async16(&Bs[(w * 32 + i * 8) * 64], Wt + (size_t)(n0 + row) * 256 + kt + scol);
    }
    __syncthreads();
#pragma unroll
    for (int kk = 0; kk < 2; ++kk) {
      bf16x8 af[4], bff[4];
#pragma unroll
      for (int m = 0; m < 4; ++m)
        af[m] = *(const bf16x8*)(&As[(wr + m * 16 + lc) * 64 + kk * 32 + lr * 8]);
#pragma unroll
      for (int n = 0; n < 4; ++n)
        bff[n] = *(const bf16x8*)(&Bs[(wc + n * 16 + lc) * 64 + kk * 32 + lr * 8]);
#pragma unroll
      for (int m = 0; m < 4; ++m)
#pragma unroll
        for (int n = 0; n < 4; ++n)
          acc[m][n] = MFMA16(af[m], bff[n], acc[m][n]);
    }
  }

  const int jr = lr * 4;
#pragma unroll
  for (int m = 0; m < 4; ++m) {
#pragma unroll
    for (int n = 0; n < 4; ++n) {
      const int c    = n0 + wc + n * 16 + lc;
      const float al = alpha[c], be = beta[c];
      const int head = c >> 6, kd = c & 63;
#pragma unroll
      for (int j = 0; j < 4; ++j) {
        const int r  = m0 + wr + m * 16 + jr + j;
        const int b  = r / 320;
        const int qr = r - b * 320;
        q_buf[((size_t)(b * 8 + head) * 320 + qr) * 64 + kd] = f2bf(acc[m][n][j] * al + be);
      }
    }
  }
}

__global__ __launch_bounds__(256) void gemm_kvq(
    const u16* __restrict__ A, const u16* __restrict__ Wkv,
    const float* __restrict__ al_kv, const float* __restrict__ be_kv,
    u16* __restrict__ k_buf, u16* __restrict__ vt_buf,
    const u16* __restrict__ Wq,
    const float* __restrict__ al_q, const float* __restrict__ be_q,
    u16* __restrict__ q_buf,
    const float* __restrict__ attn_bias, const int* __restrict__ idxs,
    u16* __restrict__ bias_frag, int n_off) {
  __shared__ __align__(16) u16 S[16384];
  const int bid = blockIdx.x;
  if (bid < 3840) {
    gemm_kv_part(S, bid, A, Wkv, al_kv, be_kv, k_buf, vt_buf);
  } else if (bid < 4160) {
    gemm_q_part(S, bid - 3840, A, Wq, al_q, be_q, q_buf);
  } else {
    // bias (x log2e, bf16) in PV-fragment order: [h][qt4][kt40][tid320][nn2*j4]
    int i = (bid - 4160) * 256 + threadIdx.x;
    if (i < 8 * 4 * 40 * 320 * 8) {
      const int e8  = i & 7;
      const int nn  = e8 >> 2;
      const int j   = e8 & 3;
      const int tid = (i >> 3) % 320;
      int v = (i >> 3) / 320;               // (h*4+qt)*40 + kt
      const int kt = v % 40; v /= 40;
      const int qt = v & 3;
      const int h  = v >> 2;
      const int w = tid >> 6, lr = (tid >> 4) & 3, lc = tid & 15;
      const int q = qt * 80 + w * 16 + lc;
      const int k = kt * 32 + nn * 16 + lr * 4 + j;
      bias_frag[i] = f2bf(attn_bias[h * n_off + idxs[q * 1280 + k]] * LOG2E);
    }
  }
}

// ---------------- attention (R16's validated optimum) ----------------
// Block = 80 q-rows (5 waves x 16), grid 1024 = exactly 4 blocks/CU,
// 20 waves/CU. Wave-per-block scan: 4w=96us, 5w=92us, 10w=97.5us -> 5 is peak.
// KVBLK=32, ring-2 24KB, 12 x 1KB DMA segments round-robined (<=3/wave)
// + 1 bias load -> WAITBAR(1).

__global__ __launch_bounds__(320) void attn_kernel(
    const u16* __restrict__ q_buf, const u16* __restrict__ kphys,
    const u16* __restrict__ vphys, const u16* __restrict__ bias_frag,
    u16* __restrict__ o_buf) {
  __shared__ __align__(16) u16 Kb[2][2048];
  __shared__ __align__(16) u16 Vb[2][4096];
  const int tid  = threadIdx.x;          // 0..319
  const int lane = tid & 63;
  const int w    = tid >> 6;             // 0..4
  const int lr   = lane >> 4, lc = lane & 15, jr = lr * 4;
  // XCD swizzle: 128 consecutive per XCD -> 32 (b,h) groups of 4 q-tiles
  const int g   = blockIdx.x;
  const int f   = (g & 7) * 128 + (g >> 3);
  const int qt  = f & 3;
  const int bh_ = f >> 2;
  const int h = bh_ & 7, b = bh_ >> 3;
  const size_t bh = (size_t)bh_;
  const int q0 = qt * 80 + w * 16;

  bf16x8 bq0, bq1;
  {
    const u16* qp = q_buf + (bh * 320 + q0 + lc) * 64 + lr * 8;
    bq0 = *(const bf16x8*)(qp);
    bq1 = *(const bf16x8*)(qp + 32);
  }

  f32x4 oacc[8] = {};
  float lacc = 0.f;

  const u16* kt_base   = kphys + bh * (40 * 2048);
  const u16* vt_base   = vphys + bh * (40 * 4096);
  const u16* bias_base = bias_frag + (((size_t)(h * 4 + qt) * 40) * 320 + tid) * 8;

  const int ko0 = lc * 64 + ((lr ^ (lc & 7)) << 3);
  const int ko1 = lc * 64 + (((4 + lr) ^ (lc & 7)) << 3);
  const int po0 = lc * 32 + ((lr + (lc >> 1)) & 7) * 4;
  const int po1 = lc * 32 + ((4 + lr + (lc >> 1)) & 7) * 4;

  u16x8 bbA, bbB;

  // 12 segments of 512 u16 (K: 0..3, V: 4..11); wave w takes segs w, w+5, w+10
  auto issue = [&](int buf, int kt) {
#pragma unroll
    for (int i = 0; i < 3; ++i) {
      const int s = w + 5 * i;
      if (s < 12) {
        if (s < 4)
          async16(&Kb[buf][s * 512], kt_base + kt * 2048 + s * 512 + lane * 8);
        else
          async16(&Vb[buf][(s - 4) * 512], vt_base + kt * 4096 + (s - 4) * 512 + lane * 8);
      }
    }
  };
  auto gbias = [&](int kt, u16x8* dst) {
    *dst = *(const u16x8*)(bias_base + (size_t)kt * 2560);
  };

  auto compute = [&](int buf, const u16x8* bb) {
    const u16* Ksb = Kb[buf];
    const u16* Vsb = Vb[buf];
    const u16* bptr = (const u16*)bb;

    f32x4 s[2];
    __builtin_amdgcn_s_setprio(1);
#pragma unroll
    for (int n = 0; n < 2; ++n) {
      const bf16x8 kf0 = *(const bf16x8*)(Ksb + n * 1024 + ko0);
      const bf16x8 kf1 = *(const bf16x8*)(Ksb + n * 1024 + ko1);
      f32x4 t;
#pragma unroll
      for (int j = 0; j < 4; ++j) t[j] = bf2f(bptr[n * 4 + j]);
      t = MFMA16(kf0, bq0, t);
      t = MFMA16(kf1, bq1, t);
      s[n] = t;
    }
    __builtin_amdgcn_s_setprio(0);

    s16x4 pa[2];
    float ssum = 0.f;
#pragma unroll
    for (int n = 0; n < 2; ++n) {
      u16x4 pk;
#pragma unroll
      for (int j = 0; j < 4; ++j) {
        const float e = EXP2(s[n][j]);
        ssum += e;
        pk[j] = f2bf(e);
      }
      pa[n] = __builtin_bit_cast(s16x4, pk);
    }
    lacc += ssum;

    __builtin_amdgcn_s_setprio(1);
#pragma unroll
    for (int nc = 0; nc < 8; ++nc) {
      const u16* vrow = Vsb + nc * 512;
      const s16x4 vf0 = __builtin_bit_cast(s16x4, *(const u16x4*)(vrow + po0));
      const s16x4 vf1 = __builtin_bit_cast(s16x4, *(const u16x4*)(vrow + po1));
      oacc[nc] = MFMA16K16(pa[0], vf0, oacc[nc]);
      oacc[nc] = MFMA16K16(pa[1], vf1, oacc[nc]);
    }
    __builtin_amdgcn_s_setprio(0);
  };

#define WAITBAR(N)                                                       \
  asm volatile("s_waitcnt vmcnt(" #N ") lgkmcnt(0)" ::: "memory");       \
  __builtin_amdgcn_s_barrier();

  issue(0, 0);
  gbias(0, &bbA);
  WAITBAR(1)   // tile0's DMAs done; bias0 may linger (compiler waits at use)

#pragma unroll 1
  for (int t = 0; t < 40; t += 2) {
    issue(1, t + 1);
    gbias(t + 1, &bbB);
    compute(0, &bbA);
    WAITBAR(1)
    if (t + 2 < 40) { issue(0, t + 2); gbias(t + 2, &bbA); }
    compute(1, &bbB);
    WAITBAR(1)
  }
#undef WAITBAR

  lacc += __shfl_xor(lacc, 16);
  lacc += __shfl_xor(lacc, 32);
  float invl[4];
#pragma unroll
  for (int j = 0; j < 4; ++j) invl[j] = 1.f / __shfl(lacc, jr + j);

#pragma unroll
  for (int nc = 0; nc < 8; ++nc)
#pragma unroll
    for (int j = 0; j < 4; ++j) {
      const float xv = oacc[nc][j] * invl[j];
      const float hs = xv * fminf(fmaxf(xv + 3.f, 0.f), 6.f) * (1.f / 6.f);
      o_buf[((size_t)b * 320 + q0 + jr + j) * 1024 + h * 128 + nc * 16 + lc] = f2bf(hs);
    }
}

// ---------------- GEMM 3: out = hswish(o) @ W_p^T, BN (f32 out) ----------------
// 64x128 tile (grid 480 = ~2 blocks/CU).

__global__ __launch_bounds__(256) void gemm_p(
    const u16* __restrict__ O, const u16* __restrict__ Wt,
    const float* __restrict__ alpha, const float* __restrict__ beta,
    float* __restrict__ out) {
  __shared__ __align__(16) u16 As[64 * 64];
  __shared__ __align__(16) u16 Bs[128 * 64];
  const int tid  = threadIdx.x;
  const int lane = tid & 63;
  const int w    = tid >> 6;
  const int wr   = (w >> 1) * 32, wc = (w & 1) * 64;
  const int lr   = lane >> 4, lc = lane & 15;
  const int m0   = blockIdx.x * 64;
  const int n0   = blockIdx.y * 128;
  const int scol  = (lane & 7) * 8;
  f32x4 acc[2][4] = {};

  for (int kt = 0; kt < 1024; kt += 64) {
    if (kt) __syncthreads();
#pragma unroll
    for (int i = 0; i < 2; ++i) {
      const int row = w * 16 + i * 8 + (lane >> 3);
      async16(&As[(w * 16 + i * 8) * 64], O + (size_t)(m0 + row) * 1024 + kt + scol);
    }
#pragma unroll
    for (int i = 0; i < 4; ++i) {
      const int row = w * 32 + i * 8 + (lane >> 3);
      async16(&Bs[(w * 32 + i * 8) * 64], Wt + (size_t)(n0 + row) * 1024 + kt + scol);
    }
    __syncthreads();
#pragma unroll
    for (int kk = 0; kk < 2; ++kk) {
      bf16x8 af[2], bff[4];
#pragma unroll
      for (int m = 0; m < 2; ++m)
        af[m] = *(const bf16x8*)(&As[(wr + m * 16 + lc) * 64 + kk * 32 + lr * 8]);
#pragma unroll
      for (int n = 0; n < 4; ++n)
        bff[n] = *(const bf16x8*)(&Bs[(wc + n * 16 + lc) * 64 + kk * 32 + lr * 8]);
#pragma unroll
      for (int m = 0; m < 2; ++m)
#pragma unroll
        for (int n = 0; n < 4; ++n)
          acc[m][n] = MFMA16(af[m], bff[n], acc[m][n]);
    }
  }

  const int jr = lr * 4;
#pragma unroll
  for (int m = 0; m < 2; ++m) {
#pragma unroll
    for (int n = 0; n < 4; ++n) {
      const int c = n0 + wc + n * 16 + lc;   // < 384
      const float al = alpha[c], be = beta[c];
#pragma unroll
      for (int j = 0; j < 4; ++j) {
        const int r = m0 + wr + m * 16 + jr + j;
        out[(size_t)r * 384 + c] = acc[m][n][j] * al + be;
      }
    }
  }
}

// ---------------- launch ----------------

extern "C" void kernel_launch(void* const* d_in, const int* in_sizes, int n_in,
                              void* d_out, int out_size, void* d_ws, size_t ws_size,
                              hipStream_t stream) {
  const float* x      = (const float*)d_in[0];
  const float* W_kv   = (const float*)d_in[1];
  const float* g_kv   = (const float*)d_in[2];
  const float* b_kv   = (const float*)d_in[3];
  const float* rm_kv  = (const float*)d_in[4];
  const float* rv_kv  = (const float*)d_in[5];
  const float* W_q    = (const float*)d_in[6];
  const float* g_q    = (const float*)d_in[7];
  const float* b_q    = (const float*)d_in[8];
  const float* rm_q   = (const float*)d_in[9];
  const float* rv_q   = (const float*)d_in[10];
  const float* W_p    = (const float*)d_in[11];
  const float* g_p    = (const float*)d_in[12];
  const float* b_p    = (const float*)d_in[13];
  const float* rm_p   = (const float*)d_in[14];
  const float* rv_p   = (const float*)d_in[15];
  const float* attn_bias = (const float*)d_in[16];
  const int*   bias_idxs = (const int*)d_in[17];
  const int n_off = in_sizes[16] / 8;

  char* ws = (char*)d_ws;
  size_t off = 0;
  auto alloc = [&](size_t bytes) -> void* {
    void* p = ws + off;
    off += (bytes + 255) & ~(size_t)255;
    return p;
  };
  u16* x_bf    = (u16*)alloc((size_t)40960 * 256 * 2);
  u16* wkv_bf  = (u16*)alloc((size_t)1536 * 256 * 2);
  u16* wq_bf   = (u16*)alloc((size_t)512 * 256 * 2);
  u16* wp_bf   = (u16*)alloc((size_t)384 * 1024 * 2);
  float* al_kv = (float*)alloc(1536 * 4);
  float* be_kv = (float*)alloc(1536 * 4);
  float* al_q  = (float*)alloc(512 * 4);
  float* be_q  = (float*)alloc(512 * 4);
  float* al_p  = (float*)alloc(384 * 4);
  float* be_p  = (float*)alloc(384 * 4);
  u16* k_buf   = (u16*)alloc((size_t)256 * 40 * 2048 * 2);
  u16* vt_buf  = (u16*)alloc((size_t)256 * 40 * 4096 * 2);
  u16* q_buf   = (u16*)alloc((size_t)32 * 8 * 320 * 64 * 2);
  u16* bias_fr = (u16*)alloc((size_t)8 * 4 * 40 * 320 * 8 * 2);
  u16* o_buf   = (u16*)alloc((size_t)32 * 320 * 1024 * 2);
  (void)ws_size; (void)n_in; (void)out_size;

  prep_all<<<11146, 256, 0, stream>>>(
      x, x_bf, W_kv, W_q, W_p, wkv_bf, wq_bf, wp_bf,
      g_kv, b_kv, rm_kv, rv_kv, al_kv, be_kv,
      g_q, b_q, rm_q, rv_q, al_q, be_q,
      g_p, b_p, rm_p, rv_p, al_p, be_p);

  gemm_kvq<<<16960, 256, 0, stream>>>(
      x_bf, wkv_bf, al_kv, be_kv, k_buf, vt_buf,
      wq_bf, al_q, be_q, q_buf,
      attn_bias, bias_idxs, bias_fr, n_off);

  attn_kernel<<<dim3(1024), 320, 0, stream>>>(q_buf, k_buf, vt_buf, bias_fr, o_buf);
  gemm_p<<<dim3(160, 3), 256, 0, stream>>>(o_buf, wp_bf, al_p, be_p, (float*)d_out);
}

// Round 20
// 174.456 us; speedup vs baseline: 1.0171x; 1.0171x over previous
//
#include <hip/hip_runtime.h>
#include <hip/hip_bf16.h>
#include <cstdint>
#include <cstddef>

typedef unsigned short u16;
typedef __bf16 bf16x8 __attribute__((ext_vector_type(8)));
typedef float  f32x4  __attribute__((ext_vector_type(4)));
typedef u16    u16x8  __attribute__((ext_vector_type(8)));
typedef u16    u16x4  __attribute__((ext_vector_type(4)));
typedef short  s16x4  __attribute__((ext_vector_type(4)));

#define MFMA16(A_, B_, C_) __builtin_amdgcn_mfma_f32_16x16x32_bf16((A_), (B_), (C_), 0, 0, 0)
#define MFMA16K16(A_, B_, C_) __builtin_amdgcn_mfma_f32_16x16x16bf16_1k((A_), (B_), (C_), 0, 0, 0)

#define LOG2E 1.4426950408889634f

#if __has_builtin(__builtin_amdgcn_exp2f)
#define EXP2(x) __builtin_amdgcn_exp2f(x)
#else
#define EXP2(x) exp2f(x)
#endif

__device__ __forceinline__ u16 f2bf(float f) {
  return __builtin_bit_cast(u16, (__bf16)f);
}
__device__ __forceinline__ float bf2f(u16 v) {
  return (float)__builtin_bit_cast(__bf16, v);
}

// async global->LDS, 16B per lane. lds must be wave-uniform base; HW adds lane*16.
__device__ __forceinline__ void async16(u16* lds, const u16* g) {
  __builtin_amdgcn_global_load_lds(
      (const __attribute__((address_space(1))) unsigned int*)g,
      (__attribute__((address_space(3))) unsigned int*)lds, 16, 0, 0);
}

// ---------------- fused prep: x cvt + weight cvts + bn folds + bias table ----------------

__device__ __forceinline__ void cvt4(const float* src, u16* dst, int i) {
  const float4 v = ((const float4*)src)[i];
  u16x4 o;
  o[0] = f2bf(v.x); o[1] = f2bf(v.y); o[2] = f2bf(v.z); o[3] = f2bf(v.w);
  ((u16x4*)dst)[i] = o;
}

__device__ __forceinline__ void bn1(const float* g, const float* b, const float* rm,
                                    const float* rv, float* alpha, float* beta,
                                    int i, float scale) {
  float a0 = g[i] * rsqrtf(rv[i] + 1e-5f);
  alpha[i] = a0 * scale;
  beta[i]  = (b[i] - rm[i] * a0) * scale;
}

__global__ void prep_all(
    const float* __restrict__ x, u16* __restrict__ x_bf,
    const float* __restrict__ Wkv, const float* __restrict__ Wq, const float* __restrict__ Wp,
    u16* __restrict__ wkv_bf, u16* __restrict__ wq_bf, u16* __restrict__ wp_bf,
    const float* __restrict__ g_kv, const float* __restrict__ b_kv,
    const float* __restrict__ rm_kv, const float* __restrict__ rv_kv,
    float* __restrict__ al_kv, float* __restrict__ be_kv,
    const float* __restrict__ g_q, const float* __restrict__ b_q,
    const float* __restrict__ rm_q, const float* __restrict__ rv_q,
    float* __restrict__ al_q, float* __restrict__ be_q,
    const float* __restrict__ g_p, const float* __restrict__ b_p,
    const float* __restrict__ rm_p, const float* __restrict__ rv_p,
    float* __restrict__ al_p, float* __restrict__ be_p,
    const float* __restrict__ attn_bias, const int* __restrict__ idxs,
    u16* __restrict__ bias_frag, int n_off) {
  const int bid = blockIdx.x, t = threadIdx.x;
  if (bid < 10240) {                       // x: 2621440 float4
    cvt4(x, x_bf, bid * 256 + t);
  } else if (bid < 10624) {
    cvt4(Wkv, wkv_bf, (bid - 10240) * 256 + t);
  } else if (bid < 10752) {
    cvt4(Wq, wq_bf, (bid - 10624) * 256 + t);
  } else if (bid < 11136) {
    cvt4(Wp, wp_bf, (bid - 10752) * 256 + t);
  } else if (bid < 11142) {
    bn1(g_kv, b_kv, rm_kv, rv_kv, al_kv, be_kv, (bid - 11136) * 256 + t, 1.0f);
  } else if (bid < 11144) {
    bn1(g_q, b_q, rm_q, rv_q, al_q, be_q, (bid - 11142) * 256 + t, 0.125f * LOG2E);
  } else if (bid < 11146) {
    const int i = (bid - 11144) * 256 + t;
    if (i < 384) bn1(g_p, b_p, rm_p, rv_p, al_p, be_p, i, 1.0f);
  } else {
    // bias (x log2e, bf16) in PV-fragment order: [h][qt4][kt40][tid320][nn2*j4]
    int i = (bid - 11146) * 256 + t;
    if (i < 8 * 4 * 40 * 320 * 8) {
      const int e8  = i & 7;
      const int nn  = e8 >> 2;
      const int j   = e8 & 3;
      const int tid = (i >> 3) % 320;
      int v = (i >> 3) / 320;               // (h*4+qt)*40 + kt
      const int kt = v % 40; v /= 40;
      const int qt = v & 3;
      const int h  = v >> 2;
      const int w = tid >> 6, lr = (tid >> 4) & 3, lc = tid & 15;
      const int q = qt * 80 + w * 16 + lc;
      const int k = kt * 32 + nn * 16 + lr * 4 + j;
      bias_frag[i] = f2bf(attn_bias[h * n_off + idxs[q * 1280 + k]] * LOG2E);
    }
  }
}

// ---------------- fused GEMM: kv (LDS-repack epilogue) + q ----------------
// K phys per (bh, kt32): 32 rows x 64ch, 16B chunk c at c^(r&7)     (b128 reads)
// V phys: 128 d x 32 keys, 8B chunk hc at (hc+(d>>1))&7             (b64 reads)

__device__ __forceinline__ void gemm_kv_part(
    u16* S, int bid,
    const u16* __restrict__ A, const u16* __restrict__ Wt,
    const float* __restrict__ alpha, const float* __restrict__ beta,
    u16* __restrict__ k_buf, u16* __restrict__ vt_buf) {
  u16* As = S;
  u16* Bs = S + 8192;
  const int tid  = threadIdx.x;
  const int lane = tid & 63;
  const int w    = tid >> 6;
  const int wr   = (w >> 1) * 64, wc = (w & 1) * 64;
  const int lr   = lane >> 4, lc = lane & 15;
  const int m0   = (bid % 320) * 128;
  const int n0   = (bid / 320) * 128;
  const int scol  = (lane & 7) * 8;
  f32x4 acc[4][4] = {};

  for (int kt = 0; kt < 256; kt += 64) {
    if (kt) __syncthreads();
#pragma unroll
    for (int i = 0; i < 4; ++i) {
      const int row = w * 32 + i * 8 + (lane >> 3);
      async16(&As[(w * 32 + i * 8) * 64], A  + (size_t)(m0 + row) * 256 + kt + scol);
      async16(&Bs[(w * 32 + i * 8) * 64], Wt + (size_t)(n0 + row) * 256 + kt + scol);
    }
    __syncthreads();
#pragma unroll
    for (int kk = 0; kk < 2; ++kk) {
      bf16x8 af[4], bff[4];
#pragma unroll
      for (int m = 0; m < 4; ++m)
        af[m] = *(const bf16x8*)(&As[(wr + m * 16 + lc) * 64 + kk * 32 + lr * 8]);
#pragma unroll
      for (int n = 0; n < 4; ++n)
        bff[n] = *(const bf16x8*)(&Bs[(wc + n * 16 + lc) * 64 + kk * 32 + lr * 8]);
#pragma unroll
      for (int m = 0; m < 4; ++m)
#pragma unroll
        for (int n = 0; n < 4; ++n)
          acc[m][n] = MFMA16(af[m], bff[n], acc[m][n]);
    }
  }

  __syncthreads();
  const int jr   = lr * 4;
  const int b    = m0 / 1280;
  const int np0  = m0 - b * 1280;
  const int kt0  = np0 >> 5;
  const int hh   = w & 1;
  const int c0   = n0 + hh * 64;
  const int head = c0 / 192;
  const int rem  = c0 - head * 192;
  u16* R = S + hh * 8192;
  (void)head;

#pragma unroll
  for (int m = 0; m < 4; ++m) {
    const int lrow = (w >> 1) * 64 + m * 16 + jr;
    const int ktl  = lrow >> 5;
    const int kl   = lrow & 31;
#pragma unroll
    for (int n = 0; n < 4; ++n) {
      const int ch = n * 16 + lc;
      const int c  = c0 + ch;
      const float al = alpha[c], be = beta[c];
      if (rem == 0) {
#pragma unroll
        for (int j = 0; j < 4; ++j) {
          const int r = kl + j;
          R[ktl * 2048 + (r << 6) + (((ch >> 3) ^ (r & 7)) << 3) + (ch & 7)] =
              f2bf(acc[m][n][j] * al + be);
        }
      } else {
        const int d = (rem - 64) + ch;
        u16x4 pk;
#pragma unroll
        for (int j = 0; j < 4; ++j) pk[j] = f2bf(acc[m][n][j] * al + be);
        *(u16x4*)(&R[ktl * 2048 + ch * 32 + ((((kl >> 2) + (d >> 1)) & 7) << 2)]) = pk;
      }
    }
  }
  __syncthreads();

#pragma unroll
  for (int g2 = 0; g2 < 2; ++g2) {
    const int c0g  = n0 + g2 * 64;
    const int hd   = c0g / 192;
    const int remg = c0g - hd * 192;
    const size_t bhg = (size_t)(b * 8 + hd);
    const u16* Rg = S + g2 * 8192;
    if (remg == 0) {
      u16* dst = k_buf + ((bhg * 40 + kt0) << 11);
#pragma unroll
      for (int i = 0; i < 4; ++i)
        *(u16x8*)(dst + i * 2048 + tid * 8) = *(const u16x8*)(Rg + i * 2048 + tid * 8);
    } else {
      const int dbase = remg - 64;
#pragma unroll
      for (int i = 0; i < 4; ++i)
        *(u16x8*)(vt_buf + ((bhg * 40 + kt0 + i) << 12) + dbase * 32 + tid * 8) =
            *(const u16x8*)(Rg + i * 2048 + tid * 8);
    }
  }
}

__device__ __forceinline__ int sub_src_row(int qr) {
  if (qr < 256) return ((qr >> 4) * 64) + ((qr & 15) * 2);
  int rr = qr - 256;
  return 1024 + ((rr >> 3) * 32) + ((rr & 7) * 2);
}

__device__ __forceinline__ void gemm_q_part(
    u16* S, int id2,
    const u16* __restrict__ X, const u16* __restrict__ Wt,
    const float* __restrict__ alpha, const float* __restrict__ beta,
    u16* __restrict__ q_buf) {
  u16* As = S;
  u16* Bs = S + 8192;
  const int tid  = threadIdx.x;
  const int lane = tid & 63;
  const int w    = tid >> 6;
  const int wr   = (w >> 1) * 64, wc = (w & 1) * 64;
  const int lr   = lane >> 4, lc = lane & 15;
  const int m0   = (id2 % 80) * 128;
  const int n0   = (id2 / 80) * 128;
  const int scol  = (lane & 7) * 8;
  f32x4 acc[4][4] = {};

  for (int kt = 0; kt < 256; kt += 64) {
    if (kt) __syncthreads();
#pragma unroll
    for (int i = 0; i < 4; ++i) {
      const int row = w * 32 + i * 8 + (lane >> 3);
      const int gr  = m0 + row;
      const int bb  = gr / 320;
      const int qr  = gr - bb * 320;
      async16(&As[(w * 32 + i * 8) * 64],
              X + (size_t)(bb * 1280 + sub_src_row(qr)) * 256 + kt + scol);
      async16(&Bs[(w * 32 + i * 8) * 64], Wt + (size_t)(n0 + row) * 256 + kt + scol);
    }
    __syncthreads();
#pragma unroll
    for (int kk = 0; kk < 2; ++kk) {
      bf16x8 af[4], bff[4];
#pragma unroll
      for (int m = 0; m < 4; ++m)
        af[m] = *(const bf16x8*)(&As[(wr + m * 16 + lc) * 64 + kk * 32 + lr * 8]);
#pragma unroll
      for (int n = 0; n < 4; ++n)
        bff[n] = *(const bf16x8*)(&Bs[(wc + n * 16 + lc) * 64 + kk * 32 + lr * 8]);
#pragma unroll
      for (int m = 0; m < 4; ++m)
#pragma unroll
        for (int n = 0; n < 4; ++n)
          acc[m][n] = MFMA16(af[m], bff[n], acc[m][n]);
    }
  }

  const int jr = lr * 4;
#pragma unroll
  for (int m = 0; m < 4; ++m) {
#pragma unroll
    for (int n = 0; n < 4; ++n) {
      const int c    = n0 + wc + n * 16 + lc;
      const float al = alpha[c], be = beta[c];
      const int head = c >> 6, kd = c & 63;
#pragma unroll
      for (int j = 0; j < 4; ++j) {
        const int r  = m0 + wr + m * 16 + jr + j;
        const int b  = r / 320;
        const int qr = r - b * 320;
        q_buf[((size_t)(b * 8 + head) * 320 + qr) * 64 + kd] = f2bf(acc[m][n][j] * al + be);
      }
    }
  }
}

__global__ __launch_bounds__(256) void gemm_kvq(
    const u16* __restrict__ A, const u16* __restrict__ Wkv,
    const float* __restrict__ al_kv, const float* __restrict__ be_kv,
    u16* __restrict__ k_buf, u16* __restrict__ vt_buf,
    const u16* __restrict__ Wq,
    const float* __restrict__ al_q, const float* __restrict__ be_q,
    u16* __restrict__ q_buf) {
  __shared__ __align__(16) u16 S[16384];
  const int bid = blockIdx.x;
  if (bid < 3840) {
    gemm_kv_part(S, bid, A, Wkv, al_kv, be_kv, k_buf, vt_buf);
  } else {
    gemm_q_part(S, bid - 3840, A, Wq, al_q, be_q, q_buf);
  }
}

// ---------------- attention (validated optimum) ----------------
// Block = 80 q-rows (5 waves x 16), grid 1024 = exactly 4 blocks/CU,
// 20 waves/CU. Wave-per-block scan: 4w=96us, 5w=92us, 10w=97.5us -> 5 is peak.
// KVBLK=32, ring-2 24KB, 12 x 1KB DMA segments round-robined (<=3/wave)
// + 1 bias load -> WAITBAR(1).

__global__ __launch_bounds__(320) void attn_kernel(
    const u16* __restrict__ q_buf, const u16* __restrict__ kphys,
    const u16* __restrict__ vphys, const u16* __restrict__ bias_frag,
    u16* __restrict__ o_buf) {
  __shared__ __align__(16) u16 Kb[2][2048];
  __shared__ __align__(16) u16 Vb[2][4096];
  const int tid  = threadIdx.x;          // 0..319
  const int lane = tid & 63;
  const int w    = tid >> 6;             // 0..4
  const int lr   = lane >> 4, lc = lane & 15, jr = lr * 4;
  // XCD swizzle: 128 consecutive per XCD -> 32 (b,h) groups of 4 q-tiles
  const int g   = blockIdx.x;
  const int f   = (g & 7) * 128 + (g >> 3);
  const int qt  = f & 3;
  const int bh_ = f >> 2;
  const int h = bh_ & 7, b = bh_ >> 3;
  const size_t bh = (size_t)bh_;
  const int q0 = qt * 80 + w * 16;

  bf16x8 bq0, bq1;
  {
    const u16* qp = q_buf + (bh * 320 + q0 + lc) * 64 + lr * 8;
    bq0 = *(const bf16x8*)(qp);
    bq1 = *(const bf16x8*)(qp + 32);
  }

  f32x4 oacc[8] = {};
  float lacc = 0.f;

  const u16* kt_base   = kphys + bh * (40 * 2048);
  const u16* vt_base   = vphys + bh * (40 * 4096);
  const u16* bias_base = bias_frag + (((size_t)(h * 4 + qt) * 40) * 320 + tid) * 8;

  const int ko0 = lc * 64 + ((lr ^ (lc & 7)) << 3);
  const int ko1 = lc * 64 + (((4 + lr) ^ (lc & 7)) << 3);
  const int po0 = lc * 32 + ((lr + (lc >> 1)) & 7) * 4;
  const int po1 = lc * 32 + ((4 + lr + (lc >> 1)) & 7) * 4;

  u16x8 bbA, bbB;

  // 12 segments of 512 u16 (K: 0..3, V: 4..11); wave w takes segs w, w+5, w+10
  auto issue = [&](int buf, int kt) {
#pragma unroll
    for (int i = 0; i < 3; ++i) {
      const int s = w + 5 * i;
      if (s < 12) {
        if (s < 4)
          async16(&Kb[buf][s * 512], kt_base + kt * 2048 + s * 512 + lane * 8);
        else
          async16(&Vb[buf][(s - 4) * 512], vt_base + kt * 4096 + (s - 4) * 512 + lane * 8);
      }
    }
  };
  auto gbias = [&](int kt, u16x8* dst) {
    *dst = *(const u16x8*)(bias_base + (size_t)kt * 2560);
  };

  auto compute = [&](int buf, const u16x8* bb) {
    const u16* Ksb = Kb[buf];
    const u16* Vsb = Vb[buf];
    const u16* bptr = (const u16*)bb;

    f32x4 s[2];
    __builtin_amdgcn_s_setprio(1);
#pragma unroll
    for (int n = 0; n < 2; ++n) {
      const bf16x8 kf0 = *(const bf16x8*)(Ksb + n * 1024 + ko0);
      const bf16x8 kf1 = *(const bf16x8*)(Ksb + n * 1024 + ko1);
      f32x4 t;
#pragma unroll
      for (int j = 0; j < 4; ++j) t[j] = bf2f(bptr[n * 4 + j]);
      t = MFMA16(kf0, bq0, t);
      t = MFMA16(kf1, bq1, t);
      s[n] = t;
    }
    __builtin_amdgcn_s_setprio(0);

    s16x4 pa[2];
    float ssum = 0.f;
#pragma unroll
    for (int n = 0; n < 2; ++n) {
      u16x4 pk;
#pragma unroll
      for (int j = 0; j < 4; ++j) {
        const float e = EXP2(s[n][j]);
        ssum += e;
        pk[j] = f2bf(e);
      }
      pa[n] = __builtin_bit_cast(s16x4, pk);
    }
    lacc += ssum;

    __builtin_amdgcn_s_setprio(1);
#pragma unroll
    for (int nc = 0; nc < 8; ++nc) {
      const u16* vrow = Vsb + nc * 512;
      const s16x4 vf0 = __builtin_bit_cast(s16x4, *(const u16x4*)(vrow + po0));
      const s16x4 vf1 = __builtin_bit_cast(s16x4, *(const u16x4*)(vrow + po1));
      oacc[nc] = MFMA16K16(pa[0], vf0, oacc[nc]);
      oacc[nc] = MFMA16K16(pa[1], vf1, oacc[nc]);
    }
    __builtin_amdgcn_s_setprio(0);
  };

#define WAITBAR(N)                                                       \
  asm volatile("s_waitcnt vmcnt(" #N ") lgkmcnt(0)" ::: "memory");       \
  __builtin_amdgcn_s_barrier();

  issue(0, 0);
  gbias(0, &bbA);
  WAITBAR(1)   // tile0's DMAs done; bias0 may linger (compiler waits at use)

#pragma unroll 1
  for (int t = 0; t < 40; t += 2) {
    issue(1, t + 1);
    gbias(t + 1, &bbB);
    compute(0, &bbA);
    WAITBAR(1)
    if (t + 2 < 40) { issue(0, t + 2); gbias(t + 2, &bbA); }
    compute(1, &bbB);
    WAITBAR(1)
  }
#undef WAITBAR

  lacc += __shfl_xor(lacc, 16);
  lacc += __shfl_xor(lacc, 32);
  float invl[4];
#pragma unroll
  for (int j = 0; j < 4; ++j) invl[j] = 1.f / __shfl(lacc, jr + j);

#pragma unroll
  for (int nc = 0; nc < 8; ++nc)
#pragma unroll
    for (int j = 0; j < 4; ++j) {
      const float xv = oacc[nc][j] * invl[j];
      const float hs = xv * fminf(fmaxf(xv + 3.f, 0.f), 6.f) * (1.f / 6.f);
      o_buf[((size_t)b * 320 + q0 + jr + j) * 1024 + h * 128 + nc * 16 + lc] = f2bf(hs);
    }
}

// ---------------- GEMM 3: out = hswish(o) @ W_p^T, BN (f32 out) ----------------
// 64x128 tile (grid 480 = ~2 blocks/CU).

__global__ __launch_bounds__(256) void gemm_p(
    const u16* __restrict__ O, const u16* __restrict__ Wt,
    const float* __restrict__ alpha, const float* __restrict__ beta,
    float* __restrict__ out) {
  __shared__ __align__(16) u16 As[64 * 64];
  __shared__ __align__(16) u16 Bs[128 * 64];
  const int tid  = threadIdx.x;
  const int lane = tid & 63;
  const int w    = tid >> 6;
  const int wr   = (w >> 1) * 32, wc = (w & 1) * 64;
  const int lr   = lane >> 4, lc = lane & 15;
  const int m0   = blockIdx.x * 64;
  const int n0   = blockIdx.y * 128;
  const int scol  = (lane & 7) * 8;
  f32x4 acc[2][4] = {};

  for (int kt = 0; kt < 1024; kt += 64) {
    if (kt) __syncthreads();
#pragma unroll
    for (int i = 0; i < 2; ++i) {
      const int row = w * 16 + i * 8 + (lane >> 3);
      async16(&As[(w * 16 + i * 8) * 64], O + (size_t)(m0 + row) * 1024 + kt + scol);
    }
#pragma unroll
    for (int i = 0; i < 4; ++i) {
      const int row = w * 32 + i * 8 + (lane >> 3);
      async16(&Bs[(w * 32 + i * 8) * 64], Wt + (size_t)(n0 + row) * 1024 + kt + scol);
    }
    __syncthreads();
#pragma unroll
    for (int kk = 0; kk < 2; ++kk) {
      bf16x8 af[2], bff[4];
#pragma unroll
      for (int m = 0; m < 2; ++m)
        af[m] = *(const bf16x8*)(&As[(wr + m * 16 + lc) * 64 + kk * 32 + lr * 8]);
#pragma unroll
      for (int n = 0; n < 4; ++n)
        bff[n] = *(const bf16x8*)(&Bs[(wc + n * 16 + lc) * 64 + kk * 32 + lr * 8]);
#pragma unroll
      for (int m = 0; m < 2; ++m)
#pragma unroll
        for (int n = 0; n < 4; ++n)
          acc[m][n] = MFMA16(af[m], bff[n], acc[m][n]);
    }
  }

  const int jr = lr * 4;
#pragma unroll
  for (int m = 0; m < 2; ++m) {
#pragma unroll
    for (int n = 0; n < 4; ++n) {
      const int c = n0 + wc + n * 16 + lc;   // < 384
      const float al = alpha[c], be = beta[c];
#pragma unroll
      for (int j = 0; j < 4; ++j) {
        const int r = m0 + wr + m * 16 + jr + j;
        out[(size_t)r * 384 + c] = acc[m][n][j] * al + be;
      }
    }
  }
}

// ---------------- launch ----------------

extern "C" void kernel_launch(void* const* d_in, const int* in_sizes, int n_in,
                              void* d_out, int out_size, void* d_ws, size_t ws_size,
                              hipStream_t stream) {
  const float* x      = (const float*)d_in[0];
  const float* W_kv   = (const float*)d_in[1];
  const float* g_kv   = (const float*)d_in[2];
  const float* b_kv   = (const float*)d_in[3];
  const float* rm_kv  = (const float*)d_in[4];
  const float* rv_kv  = (const float*)d_in[5];
  const float* W_q    = (const float*)d_in[6];
  const float* g_q    = (const float*)d_in[7];
  const float* b_q    = (const float*)d_in[8];
  const float* rm_q   = (const float*)d_in[9];
  const float* rv_q   = (const float*)d_in[10];
  const float* W_p    = (const float*)d_in[11];
  const float* g_p    = (const float*)d_in[12];
  const float* b_p    = (const float*)d_in[13];
  const float* rm_p   = (const float*)d_in[14];
  const float* rv_p   = (const float*)d_in[15];
  const float* attn_bias = (const float*)d_in[16];
  const int*   bias_idxs = (const int*)d_in[17];
  const int n_off = in_sizes[16] / 8;

  char* ws = (char*)d_ws;
  size_t off = 0;
  auto alloc = [&](size_t bytes) -> void* {
    void* p = ws + off;
    off += (bytes + 255) & ~(size_t)255;
    return p;
  };
  u16* x_bf    = (u16*)alloc((size_t)40960 * 256 * 2);
  u16* wkv_bf  = (u16*)alloc((size_t)1536 * 256 * 2);
  u16* wq_bf   = (u16*)alloc((size_t)512 * 256 * 2);
  u16* wp_bf   = (u16*)alloc((size_t)384 * 1024 * 2);
  float* al_kv = (float*)alloc(1536 * 4);
  float* be_kv = (float*)alloc(1536 * 4);
  float* al_q  = (float*)alloc(512 * 4);
  float* be_q  = (float*)alloc(512 * 4);
  float* al_p  = (float*)alloc(384 * 4);
  float* be_p  = (float*)alloc(384 * 4);
  u16* k_buf   = (u16*)alloc((size_t)256 * 40 * 2048 * 2);
  u16* vt_buf  = (u16*)alloc((size_t)256 * 40 * 4096 * 2);
  u16* q_buf   = (u16*)alloc((size_t)32 * 8 * 320 * 64 * 2);
  u16* bias_fr = (u16*)alloc((size_t)8 * 4 * 40 * 320 * 8 * 2);
  u16* o_buf   = (u16*)alloc((size_t)32 * 320 * 1024 * 2);
  (void)ws_size; (void)n_in; (void)out_size;

  prep_all<<<23946, 256, 0, stream>>>(
      x, x_bf, W_kv, W_q, W_p, wkv_bf, wq_bf, wp_bf,
      g_kv, b_kv, rm_kv, rv_kv, al_kv, be_kv,
      g_q, b_q, rm_q, rv_q, al_q, be_q,
      g_p, b_p, rm_p, rv_p, al_p, be_p,
      attn_bias, bias_idxs, bias_fr, n_off);

  gemm_kvq<<<4160, 256, 0, stream>>>(
      x_bf, wkv_bf, al_kv, be_kv, k_buf, vt_buf,
      wq_bf, al_q, be_q, q_buf);

  attn_kernel<<<dim3(1024), 320, 0, stream>>>(q_buf, k_buf, vt_buf, bias_fr, o_buf);
  gemm_p<<<dim3(160, 3), 256, 0, stream>>>(o_buf, wp_bf, al_p, be_p, (float*)d_out);
}